// Round 13
// baseline (599.469 us; speedup 1.0000x reference)
//
#include <hip/hip_runtime.h>

// numpy never contracts mul+add: products are rounded then added. File-wide.
// The sgemm dot uses __builtin_fmaf explicitly (OpenBLAS vfmadd231ps).
#pragma clang fp contract(off)

#define NN 512
#define DD 256
#define PCH 64   // p-values per store block

typedef int int4v __attribute__((ext_vector_type(4)));

// ---------------------------------------------------------------------------
// numpy f32 pairwise-sum leaf, n=128, AVX512 path (verified bit-exact R11):
// 16 lane-partials over stride-16 elements, vector tree
// ((q0+q1)+(q2+q3))+((q4+q5)+(q6+q7)), then reduce_add lane-halving.
// ---------------------------------------------------------------------------
__device__ __forceinline__ float np_leaf128(const float* __restrict__ x)
{
    float p[16];
    #pragma unroll
    for (int i = 0; i < 16; ++i) {
        const float q0 = x[i]       * x[i];
        const float q1 = x[i + 16]  * x[i + 16];
        const float q2 = x[i + 32]  * x[i + 32];
        const float q3 = x[i + 48]  * x[i + 48];
        const float q4 = x[i + 64]  * x[i + 64];
        const float q5 = x[i + 80]  * x[i + 80];
        const float q6 = x[i + 96]  * x[i + 96];
        const float q7 = x[i + 112] * x[i + 112];
        p[i] = ((q0 + q1) + (q2 + q3)) + ((q4 + q5) + (q6 + q7));
    }
    float q[8];
    #pragma unroll
    for (int i = 0; i < 8; ++i) q[i] = p[i] + p[i + 8];
    const float s0 = q[0] + q[4];
    const float s1 = q[1] + q[5];
    const float s2 = q[2] + q[6];
    const float s3 = q[3] + q[7];
    return (s0 + s2) + (s1 + s3);
}

// ---------------------------------------------------------------------------
// Kernel 1: per-anchor folded distance tables (bit-exact R11 arithmetic).
//   dn[a][j] = diff-class ? mat[a,j] : +inf
//   mp[a][j] = same-class && j!=a ? mat[a,j] : NaN
// mat[a,j] = relu(fl32(fl32(sq_a+sq_j) - fl32(2*dot))), sq = AVX512 pairwise,
// dot = sequential-k FMA. One block per anchor; 512 threads.
// ---------------------------------------------------------------------------
__global__ __launch_bounds__(512)
void tables_kernel(const float* __restrict__ emb,
                   const int* __restrict__ lab,
                   float* __restrict__ dn_ws,
                   float* __restrict__ mp_ws)
{
    __shared__ int   canon[NN];
    __shared__ float arow[DD];
    __shared__ float sq_a_sh;
    __shared__ int   det_lab64;

    const int a = blockIdx.x;
    const int t = threadIdx.x;   // 0..511

    // labels width canonicalization (values in [0,32): int64 staging has all
    // 256 odd int32 words zero; genuine int32 fails that w.p. 1-32^-256)
    if (t == 0) det_lab64 = 0;
    __syncthreads();
    if (t < 256 && lab[2 * t + 1] == 0) atomicAdd(&det_lab64, 1);
    __syncthreads();
    canon[t] = (det_lab64 == 256) ? lab[2 * t] : lab[t];

    if (t < DD) arow[t] = emb[(size_t)a * DD + t];
    __syncthreads();

    const float* __restrict__ xr = emb + (size_t)t * DD;
    const float sqj = np_leaf128(xr) + np_leaf128(xr + 128);
    if (t == a) sq_a_sh = sqj;

    float dot = 0.0f;
    for (int k = 0; k < DD; ++k)
        dot = __builtin_fmaf(arow[k], xr[k], dot);
    __syncthreads();   // sq_a_sh visible

    const float t1 = sq_a_sh + sqj;
    const float t2 = 2.0f * dot;       // exact scale
    float m = t1 - t2;
    m = m > 0.0f ? m : 0.0f;

    const int la = canon[a];
    dn_ws[(size_t)a * NN + t] = (canon[t] != la) ? m : __builtin_inff();
    mp_ws[(size_t)a * NN + t] = (canon[t] == la && t != a) ? m
                                                           : __builtin_nanf("");
}

// ---------------------------------------------------------------------------
// Kernel 2: pure store kernel. Block = (a, 64-p chunk): 4096 blocks x 256
// threads, ~8 blocks/CU for deep store overlap. Reads 2.25 KiB of tables,
// streams 128 KiB of coalesced int4 stores (n fastest).
// mask = (fl32(dn[n] - mp[p]) <= 0.2f); inf/NaN fold validity to 0.
// ---------------------------------------------------------------------------
__global__ __launch_bounds__(256)
void mask_kernel(const float* __restrict__ dn_ws,
                 const float* __restrict__ mp_ws,
                 int* __restrict__ out)
{
    __shared__ float dn_sh[NN];
    __shared__ float mp_sh[PCH];

    const int bid = blockIdx.x;
    const int a   = bid >> 3;          // NN/PCH == 8
    const int pc  = bid & 7;
    const int t   = threadIdx.x;       // 0..255

    dn_sh[t]       = dn_ws[(size_t)a * NN + t];
    dn_sh[t + 256] = dn_ws[(size_t)a * NN + t + 256];
    if (t < PCH) mp_sh[t] = mp_ws[(size_t)a * NN + pc * PCH + t];
    __syncthreads();

    const int tx = t & 127;            // 4 consecutive n per thread
    const int ty = t >> 7;             // 0..1 strides the p chunk
    const float d0 = dn_sh[4 * tx + 0];
    const float d1 = dn_sh[4 * tx + 1];
    const float d2 = dn_sh[4 * tx + 2];
    const float d3 = dn_sh[4 * tx + 3];

    int4v* base = (int4v*)out
                + ((size_t)a * NN + (size_t)pc * PCH) * (NN / 4) + tx;
    for (int p2 = ty; p2 < PCH; p2 += 2) {
        const float mpp = mp_sh[p2];   // LDS broadcast
        int4v r;
        r.x = ((d0 - mpp) <= 0.2f) ? 1 : 0;
        r.y = ((d1 - mpp) <= 0.2f) ? 1 : 0;
        r.z = ((d2 - mpp) <= 0.2f) ? 1 : 0;
        r.w = ((d3 - mpp) <= 0.2f) ? 1 : 0;
        base[(size_t)p2 * (NN / 4)] = r;
    }
}

// ---------------------------------------------------------------------------
// Fallback: the R11 fused kernel (verified bit-exact), used if ws < 2 MiB.
// ---------------------------------------------------------------------------
__global__ __launch_bounds__(512)
void triplet_fused_kernel(const float* __restrict__ emb,
                          const int* __restrict__ lab,
                          int* __restrict__ out)
{
    __shared__ int   canon[NN];
    __shared__ float arow[DD];
    __shared__ float dn[NN];
    __shared__ float mp[NN];
    __shared__ float sq_a_sh;
    __shared__ int   det_lab64;

    const int a = blockIdx.x;
    const int t = threadIdx.x;

    if (t == 0) det_lab64 = 0;
    __syncthreads();
    if (t < 256 && lab[2 * t + 1] == 0) atomicAdd(&det_lab64, 1);
    __syncthreads();
    canon[t] = (det_lab64 == 256) ? lab[2 * t] : lab[t];

    if (t < DD) arow[t] = emb[(size_t)a * DD + t];
    __syncthreads();

    const float* __restrict__ xr = emb + (size_t)t * DD;
    const float sqj = np_leaf128(xr) + np_leaf128(xr + 128);
    if (t == a) sq_a_sh = sqj;

    float dot = 0.0f;
    for (int k = 0; k < DD; ++k)
        dot = __builtin_fmaf(arow[k], xr[k], dot);
    __syncthreads();

    const float t1 = sq_a_sh + sqj;
    const float t2 = 2.0f * dot;
    float m = t1 - t2;
    m = m > 0.0f ? m : 0.0f;

    const int la = canon[a];
    dn[t] = (canon[t] != la) ? m : __builtin_inff();
    mp[t] = (canon[t] == la && t != a) ? m : __builtin_nanf("");
    __syncthreads();

    const int tx = t & 127;
    const int ty = t >> 7;
    const float d0 = dn[4 * tx + 0];
    const float d1 = dn[4 * tx + 1];
    const float d2 = dn[4 * tx + 2];
    const float d3 = dn[4 * tx + 3];

    int4v* base = (int4v*)out + (size_t)a * NN * (NN / 4) + tx;
    for (int p = ty; p < NN; p += 4) {
        const float mpp = mp[p];
        int4v r;
        r.x = ((d0 - mpp) <= 0.2f) ? 1 : 0;
        r.y = ((d1 - mpp) <= 0.2f) ? 1 : 0;
        r.z = ((d2 - mpp) <= 0.2f) ? 1 : 0;
        r.w = ((d3 - mpp) <= 0.2f) ? 1 : 0;
        base[(size_t)p * (NN / 4)] = r;
    }
}

// ---------------------------------------------------------------------------
extern "C" void kernel_launch(void* const* d_in, const int* in_sizes, int n_in,
                              void* d_out, int out_size, void* d_ws, size_t ws_size,
                              hipStream_t stream)
{
    const float* emb    = (const float*)d_in[0];
    const int*   labels = (const int*)d_in[1];
    int*         out    = (int*)d_out;

    const size_t tbl = (size_t)NN * NN * sizeof(float);   // 1 MiB each
    if (ws_size >= 2 * tbl) {
        float* dn_ws = (float*)d_ws;
        float* mp_ws = (float*)((char*)d_ws + tbl);
        tables_kernel<<<NN, 512, 0, stream>>>(emb, labels, dn_ws, mp_ws);
        mask_kernel<<<NN * (NN / PCH), 256, 0, stream>>>(dn_ws, mp_ws, out);
    } else {
        triplet_fused_kernel<<<NN, 512, 0, stream>>>(emb, labels, out);
    }
}

// Round 14
// 566.249 us; speedup vs baseline: 1.0587x; 1.0587x over previous
//
#include <hip/hip_runtime.h>

// numpy never contracts mul+add: products are rounded then added. File-wide.
// The sgemm dot uses __builtin_fmaf explicitly (OpenBLAS vfmadd231ps).
#pragma clang fp contract(off)

#define NN 512
#define DD 256

typedef int int4v __attribute__((ext_vector_type(4)));

// ---------------------------------------------------------------------------
// numpy f32 pairwise-sum leaf, n=128, AVX512 path (verified bit-exact R11):
// 16 lane-partials over stride-16 elements, vector tree
// ((q0+q1)+(q2+q3))+((q4+q5)+(q6+q7)), then reduce_add lane-halving.
// ---------------------------------------------------------------------------
__device__ __forceinline__ float np_leaf128(const float* __restrict__ x)
{
    float p[16];
    #pragma unroll
    for (int i = 0; i < 16; ++i) {
        const float q0 = x[i]       * x[i];
        const float q1 = x[i + 16]  * x[i + 16];
        const float q2 = x[i + 32]  * x[i + 32];
        const float q3 = x[i + 48]  * x[i + 48];
        const float q4 = x[i + 64]  * x[i + 64];
        const float q5 = x[i + 80]  * x[i + 80];
        const float q6 = x[i + 96]  * x[i + 96];
        const float q7 = x[i + 112] * x[i + 112];
        p[i] = ((q0 + q1) + (q2 + q3)) + ((q4 + q5) + (q6 + q7));
    }
    float q[8];
    #pragma unroll
    for (int i = 0; i < 8; ++i) q[i] = p[i] + p[i + 8];
    const float s0 = q[0] + q[4];
    const float s1 = q[1] + q[5];
    const float s2 = q[2] + q[6];
    const float s3 = q[3] + q[7];
    return (s0 + s2) + (s1 + s3);
}

// ---------------------------------------------------------------------------
// Fused TripletMarginMiner — EXACTLY the R11 structure (best so far, no d_ws:
// ws use costs ~+30us in the timed graph), with ONE change: the 512 MiB of
// mask stores are NONTEMPORAL (nt flag -> no L2 write-allocate/RFO). Theory:
// plain stores run at ~4.4 TB/s vs fillBuffer's 6.2 TB/s because store-miss
// lines are filled from HBM before overwrite; nt bypasses that.
//
//   sq   : np.sum(emb*emb,axis=1) — AVX512 pairwise leaves (above).
//   dot  : OpenBLAS sgemm — single f32 accumulator, sequential k, FMA.
//   mat  : fl32(fl32(sq_a+sq_j) - fl32(2*dot)), relu.
//   mask : sames(a,p)&(p!=a)&diffs(a,n)&(fl32(mat_an-mat_ap) <= 0.2f)
//          validity folded: dn=+inf (diff fails), mp=NaN (same fails).
// One block per anchor a; 512 threads; coalesced int4 stores, n fastest.
// ---------------------------------------------------------------------------
__global__ __launch_bounds__(512)
void triplet_kernel(const float* __restrict__ emb,
                    const int* __restrict__ lab,
                    int* __restrict__ out)
{
    __shared__ int   canon[NN];
    __shared__ float arow[DD];
    __shared__ float dn[NN];
    __shared__ float mp[NN];
    __shared__ float sq_a_sh;
    __shared__ int   det_lab64;

    const int a = blockIdx.x;
    const int t = threadIdx.x;   // 0..511

    // labels width canonicalization (values in [0,32): int64 staging has all
    // 256 odd int32 words zero; genuine int32 fails that w.p. 1-32^-256)
    if (t == 0) det_lab64 = 0;
    __syncthreads();
    if (t < 256 && lab[2 * t + 1] == 0) atomicAdd(&det_lab64, 1);
    __syncthreads();
    canon[t] = (det_lab64 == 256) ? lab[2 * t] : lab[t];

    if (t < DD) arow[t] = emb[(size_t)a * DD + t];
    __syncthreads();

    // ---- sq_j (numpy SIMD pairwise) ----
    const float* __restrict__ xr = emb + (size_t)t * DD;
    const float sqj = np_leaf128(xr) + np_leaf128(xr + 128);
    if (t == a) sq_a_sh = sqj;

    // ---- dot(a,j): sequential-k single-accumulator FMA (sgemm kernel) ----
    float dot = 0.0f;
    for (int k = 0; k < DD; ++k)
        dot = __builtin_fmaf(arow[k], xr[k], dot);
    __syncthreads();   // sq_a_sh visible

    // ---- mat[a][t], f32, numpy op tree ----
    const float t1 = sq_a_sh + sqj;
    const float t2 = 2.0f * dot;       // exact scale
    float m = t1 - t2;
    m = m > 0.0f ? m : 0.0f;

    const int la = canon[a];
    dn[t] = (canon[t] != la) ? m : __builtin_inff();
    mp[t] = (canon[t] == la && t != a) ? m : __builtin_nanf("");
    __syncthreads();

    // ---- write the 512x512 int32 slab: NONTEMPORAL coalesced int4 ----
    const int tx = t & 127;      // 4 consecutive n per thread
    const int ty = t >> 7;       // 0..3 strides p
    const float d0 = dn[4 * tx + 0];
    const float d1 = dn[4 * tx + 1];
    const float d2 = dn[4 * tx + 2];
    const float d3 = dn[4 * tx + 3];

    int4v* base = (int4v*)out + (size_t)a * NN * (NN / 4) + tx;
    for (int p = ty; p < NN; p += 4) {
        const float mpp = mp[p];             // LDS broadcast
        int4v r;
        r.x = ((d0 - mpp) <= 0.2f) ? 1 : 0;  // inf/NaN fold validity to 0
        r.y = ((d1 - mpp) <= 0.2f) ? 1 : 0;
        r.z = ((d2 - mpp) <= 0.2f) ? 1 : 0;
        r.w = ((d3 - mpp) <= 0.2f) ? 1 : 0;
        __builtin_nontemporal_store(r, base + (size_t)p * (NN / 4));
    }
}

// ---------------------------------------------------------------------------
extern "C" void kernel_launch(void* const* d_in, const int* in_sizes, int n_in,
                              void* d_out, int out_size, void* d_ws, size_t ws_size,
                              hipStream_t stream)
{
    const float* emb    = (const float*)d_in[0];
    const int*   labels = (const int*)d_in[1];
    int*         out    = (int*)d_out;
    (void)d_ws; (void)ws_size;   // deliberately unused: ws use costs ~+30us

    triplet_kernel<<<NN, 512, 0, stream>>>(emb, labels, out);
}